// Round 9
// baseline (196.686 us; speedup 1.0000x reference)
//
#include <hip/hip_runtime.h>

typedef unsigned short ushort_t;
typedef unsigned int uint_t;

#define BKT_SHIFT 7            // 128 dst-nodes per bucket
#define BKT_NODES 128
#define NBKT_MAX 800           // >= ceil(100000/128)=782
#define BCAP 8192              // slots/bucket; mean usage ~5000 (3200 real + pad)
#define EPB 8192               // edges per scatter block (512 thr x 16 in regs)
#define SCOLN (BCAP / 2 + 1024)  // LDS sorted-col capacity (real edges only)

__device__ __forceinline__ ushort_t f2bf(float f) {
    unsigned u = __float_as_uint(f);
    unsigned r = (u + 0x7FFFu + ((u >> 16) & 1u)) >> 16;   // RNE
    return (ushort_t)r;
}
__device__ __forceinline__ float bflo(uint_t u) { return __uint_as_float(u << 16); }
__device__ __forceinline__ float bfhi(uint_t u) { return __uint_as_float(u & 0xFFFF0000u); }

// ---- fat kernel: LINE-EXCLUSIVE range-claim scatter || z1 = x@W1 -------
// Round-2 PMC evidence: per-edge scattered 4B stores into shared bucket
// slots gave WRITE_SIZE=121MB for 13MB payload (9x write-amp: each 64B
// line dirtied by ~16 blocks at different times -> repeated evict+refetch).
// Fix: claims are rounded up to 16 slots (one 64B line), so every line
// belongs to exactly ONE scatter block, which writes it fully (real edges
// + sentinel -1 padding) closely in time -> write-amp ~1x.
// Per-edge atomics stay in LDS (round-2 lesson); one global claim per
// (block,bucket) (~306 per address, validated round 3).
// Lin blocks: per-node 32->16 matvec, bf16 out (GIN distributivity:
// (x_i + sum x_j)@W1 = z_i + sum z_j -> aggregate in 16-ch z-space;
// z table = 3.2 MB -> per-XCD-L2-resident, gather order irrelevant).
__global__ __launch_bounds__(512) void scatter_lin(
    const int* __restrict__ src, const int* __restrict__ dst,
    int* __restrict__ gcnt, int* __restrict__ staged,
    const float4* __restrict__ x4, const float* __restrict__ W,
    ushort_t* __restrict__ z, int E, int SBLK, int N, int NBKT)
{
    __shared__ float sW[512];
    __shared__ int lcnt[NBKT_MAX];
    __shared__ int lbase[NBKT_MAX];
    __shared__ int lcur[NBKT_MAX];
    int t = threadIdx.x, blk = blockIdx.x;
    if (blk < SBLK) {
        for (int b = t; b < NBKT; b += 512) { lcnt[b] = 0; lcur[b] = 0; }
        __syncthreads();
        int e0 = blk * EPB;
        int rd[16], rs[16];
        #pragma unroll
        for (int i = 0; i < 16; ++i) {
            int e = e0 + i * 512 + t;
            bool ok = (e < E);
            rd[i] = ok ? dst[e] : -1;
            rs[i] = ok ? src[e] : 0;
            if (ok) atomicAdd(&lcnt[rd[i] >> BKT_SHIFT], 1);
        }
        __syncthreads();
        // claim a line-aligned (multiple-of-16) range per touched bucket
        for (int b = t; b < NBKT; b += 512) {
            int padded = (lcnt[b] + 15) & ~15;
            lbase[b] = padded ? atomicAdd(&gcnt[b], padded) : 0;
        }
        __syncthreads();
        #pragma unroll
        for (int i = 0; i < 16; ++i) {
            if (rd[i] >= 0) {
                int b = rd[i] >> BKT_SHIFT;
                int r = lbase[b] + atomicAdd(&lcur[b], 1);
                if (r < BCAP)   // statistically unreachable overflow guard
                    staged[(size_t)b * BCAP + r] =
                        ((rd[i] & (BKT_NODES - 1)) << 24) | rs[i];
            }
        }
        __syncthreads();
        // fill this block's pad slots with sentinel -1 (completes the lines
        // we own; valid words have bit31 clear since dl<128, s<2^24)
        for (int b = t; b < NBKT; b += 512) {
            int cnt = lcnt[b];
            int padded = (cnt + 15) & ~15;
            int base = lbase[b];
            for (int w = cnt; w < padded; ++w) {
                int gs = base + w;
                if (gs < BCAP)
                    staged[(size_t)b * BCAP + gs] = -1;
            }
        }
    } else {
        sW[t] = W[t];                      // 32x16 = 512 floats
        __syncthreads();
        int n = (blk - SBLK) * 512 + t;
        if (n >= N) return;
        float a[16];
        #pragma unroll
        for (int c = 0; c < 16; ++c) a[c] = 0.f;
        const float4* xr = x4 + (size_t)n * 8;
        #pragma unroll
        for (int k4 = 0; k4 < 8; ++k4) {
            float4 xv = xr[k4];
            #pragma unroll
            for (int c = 0; c < 16; ++c) {
                a[c] += xv.x * sW[(k4 * 4 + 0) * 16 + c];
                a[c] += xv.y * sW[(k4 * 4 + 1) * 16 + c];
                a[c] += xv.z * sW[(k4 * 4 + 2) * 16 + c];
                a[c] += xv.w * sW[(k4 * 4 + 3) * 16 + c];
            }
        }
        uint_t w[8];
        #pragma unroll
        for (int i2 = 0; i2 < 8; ++i2)
            w[i2] = (uint_t)f2bf(a[2 * i2]) | ((uint_t)f2bf(a[2 * i2 + 1]) << 16);
        uint4* zo = (uint4*)(z + (size_t)n * 16);
        uint4 q0; q0.x = w[0]; q0.y = w[1]; q0.z = w[2]; q0.w = w[3];
        uint4 q1; q1.x = w[4]; q1.y = w[5]; q1.z = w[6]; q1.w = w[7];
        zo[0] = q0;     // cacheable: consumed by agg gathers next
        zo[1] = q1;
    }
}

// ---- shared gather + pair-shuffle MLP core (verified rounds 5/7) -------
// 2 lanes per node (sl=0/1), uint4 = 8 bf16 channels per lane.

__device__ __forceinline__ void gather_acc(
    const uint4* __restrict__ zp, const int* __restrict__ scol,
    int k, int ke, int sl, float* acc)
{
    for (; k + 8 <= ke; k += 8) {
        uint4 uu[8];
        #pragma unroll
        for (int j = 0; j < 8; ++j)
            uu[j] = zp[(size_t)scol[k + j] * 2 + sl];
        #pragma unroll
        for (int j = 0; j < 8; ++j) {
            acc[0] += bflo(uu[j].x); acc[1] += bfhi(uu[j].x);
            acc[2] += bflo(uu[j].y); acc[3] += bfhi(uu[j].y);
            acc[4] += bflo(uu[j].z); acc[5] += bfhi(uu[j].z);
            acc[6] += bflo(uu[j].w); acc[7] += bfhi(uu[j].w);
        }
    }
    for (; k < ke; ++k) {
        uint4 u = zp[(size_t)scol[k] * 2 + sl];
        acc[0] += bflo(u.x); acc[1] += bfhi(u.x);
        acc[2] += bflo(u.y); acc[3] += bfhi(u.y);
        acc[4] += bflo(u.z); acc[5] += bfhi(u.z);
        acc[6] += bflo(u.w); acc[7] += bfhi(u.w);
    }
}

// h = ReLU(acc + ba); o[16] = h @ Wb(16x32) + bb for out-ch 16*sl..16*sl+15
__device__ __forceinline__ void mlp_front(
    const float* acc, const float* sba, const float* sWb, const float* sbb,
    int sl, float* o)
{
    float h[8], hp[8];
    #pragma unroll
    for (int j = 0; j < 8; ++j) h[j] = fmaxf(acc[j] + sba[sl * 8 + j], 0.f);
    #pragma unroll
    for (int j = 0; j < 8; ++j) hp[j] = __shfl_xor(h[j], 1);
    float hl[8], hh[8];
    #pragma unroll
    for (int j = 0; j < 8; ++j) {
        hl[j] = sl ? hp[j] : h[j];     // h channels 0..7
        hh[j] = sl ? h[j] : hp[j];     // h channels 8..15
    }
    int ocb = sl * 16;
    #pragma unroll
    for (int i = 0; i < 16; ++i) o[i] = sbb[ocb + i];
    #pragma unroll
    for (int j = 0; j < 8; ++j) {
        #pragma unroll
        for (int i = 0; i < 16; ++i) {
            o[i] += hl[j] * sWb[j * 32 + ocb + i];
            o[i] += hh[j] * sWb[(j + 8) * 32 + ocb + i];
        }
    }
}

// ---- Fused sort + aggregate + MLP (round-7 structure + sentinel skip) --
// One 256-thread block per 128-node bucket (782 blocks). Phase 1: sort the
// bucket's staged run into LDS scol, skipping sentinel (-1) pad words
// (count by (node, s&3) -> 128-node Hillis scan -> ranked place). Phase 2:
// 2-lane-per-node uint4 gather + pair-shuffle MLP.
//   CHAIN:  z_next = ReLU(o)@Wc -> bf16 (feeds conv2's aggregation)
//   !CHAIN: o -> fp32 final output

template <bool CHAIN>
__global__ __launch_bounds__(256) void agg_sort_mlp(
    const ushort_t* __restrict__ zin, const int* __restrict__ staged,
    const int* __restrict__ gcnt,
    const float* __restrict__ ba,
    const float* __restrict__ Wb, const float* __restrict__ bb,
    const float* __restrict__ Wc,
    void* __restrict__ outv, int N)
{
    __shared__ float sWb[512];     // 16x32
    __shared__ float sWc[512];     // 32x16 (CHAIN only)
    __shared__ float sba[16], sbb[32];
    __shared__ int scnt[512], srel[512], scur[512];   // [node][src&3]
    __shared__ int sns[128];
    __shared__ int snode[129];
    __shared__ int scol[SCOLN];    // 20 KB; real edges only (mean 3200, +22 sigma)

    int t = threadIdx.x;
    sWb[t] = Wb[t];  sWb[t + 256] = Wb[t + 256];
    if (CHAIN) { sWc[t] = Wc[t];  sWc[t + 256] = Wc[t + 256]; }
    if (t < 16) sba[t] = ba[t];
    if (t < 32) sbb[t] = bb[t];
    scnt[t] = 0; scnt[t + 256] = 0;
    scur[t] = 0; scur[t + 256] = 0;
    __syncthreads();

    int b = blockIdx.x;
    int m = min(gcnt[b], BCAP);
    const int* sp = staged + (size_t)b * BCAP;

    // count by (node, s&3), skipping sentinels (bit31 set)
    for (int i = t; i < m; i += 256) {
        int v = sp[i];
        if (v >= 0)
            atomicAdd(&scnt[(((unsigned)v >> 24) << 2) | (v & 3)], 1);
    }
    __syncthreads();
    int c0 = 0, c1 = 0, c2 = 0, c3 = 0, tot = 0;
    if (t < 128) {
        c0 = scnt[t * 4 + 0]; c1 = scnt[t * 4 + 1];
        c2 = scnt[t * 4 + 2]; c3 = scnt[t * 4 + 3];
        tot = c0 + c1 + c2 + c3;
        sns[t] = tot;
    }
    __syncthreads();
    for (int off = 1; off < 128; off <<= 1) {   // Hillis over 128 node totals
        int add = (t < 128 && t >= off) ? sns[t - off] : 0;
        __syncthreads();
        if (t < 128) sns[t] += add;
        __syncthreads();
    }
    if (t < 128) {
        int excl = sns[t] - tot;
        srel[t * 4 + 0] = excl;
        srel[t * 4 + 1] = excl + c0;
        srel[t * 4 + 2] = excl + c0 + c1;
        srel[t * 4 + 3] = excl + c0 + c1 + c2;
        snode[t] = excl;
        if (t == 127) snode[128] = sns[127];
    }
    __syncthreads();
    // ranked place (staged run L2-hot from count pass)
    for (int i = t; i < m; i += 256) {
        int v = sp[i];
        if (v >= 0) {
            int idx = (((unsigned)v >> 24) << 2) | (v & 3);
            int p = srel[idx] + atomicAdd(&scur[idx], 1);
            if (p < SCOLN)   // statistically unreachable guard
                scol[p] = v & 0xFFFFFF;
        }
    }
    __syncthreads();

    // gather + MLP
    int ln = t >> 1, sl = t & 1;
    int base = b << BKT_SHIFT;
    int n = base + ln;
    if (n < N) {
        const uint4* zp = (const uint4*)zin;
        uint4 us = zp[(size_t)n * 2 + sl];     // self term
        float acc[8] = { bflo(us.x), bfhi(us.x), bflo(us.y), bfhi(us.y),
                         bflo(us.z), bfhi(us.z), bflo(us.w), bfhi(us.w) };
        int ks = snode[ln];
        int ke = min(snode[ln + 1], SCOLN);
        gather_acc(zp, scol, ks, ke, sl, acc);
        float o[16];
        mlp_front(acc, sba, sWb, sbb, sl, o);
        if (CHAIN) {
            // z_next[16] = ReLU(o32) @ Wc(32x16); this lane has 16 of 32 rows
            float p[16];
            #pragma unroll
            for (int zc = 0; zc < 16; ++zc) p[zc] = 0.f;
            int ocb = sl * 16;
            #pragma unroll
            for (int i = 0; i < 16; ++i) {
                float r = fmaxf(o[i], 0.f);
                #pragma unroll
                for (int zc = 0; zc < 16; ++zc)
                    p[zc] += r * sWc[(ocb + i) * 16 + zc];
            }
            float pm[8], po[8];
            #pragma unroll
            for (int k = 0; k < 8; ++k) {
                pm[k] = sl ? p[8 + k] : p[k];      // partial for my z-ch block
                po[k] = sl ? p[k] : p[8 + k];      // partial for partner's
            }
            #pragma unroll
            for (int k = 0; k < 8; ++k) po[k] = __shfl_xor(po[k], 1);
            uint_t w[4];
            #pragma unroll
            for (int k = 0; k < 4; ++k) {
                float zA = pm[2 * k]     + po[2 * k];
                float zB = pm[2 * k + 1] + po[2 * k + 1];
                w[k] = (uint_t)f2bf(zA) | ((uint_t)f2bf(zB) << 16);
            }
            uint4 q; q.x = w[0]; q.y = w[1]; q.z = w[2]; q.w = w[3];
            ((uint4*)outv)[(size_t)n * 2 + sl] = q;  // cacheable: conv2 gathers
        } else {
            float* op = (float*)outv + (size_t)n * 32 + sl * 16;
            #pragma unroll
            for (int i = 0; i < 16; ++i)
                __builtin_nontemporal_store(o[i], op + i);
        }
    }
}

// ---- Launch -------------------------------------------------------------

extern "C" void kernel_launch(void* const* d_in, const int* in_sizes, int n_in,
                              void* d_out, int out_size, void* d_ws, size_t ws_size,
                              hipStream_t stream) {
    const float* x  = (const float*)d_in[0];
    const int*   ei = (const int*)d_in[1];
    const float* W1 = (const float*)d_in[2];
    const float* b1 = (const float*)d_in[3];
    const float* W2 = (const float*)d_in[4];
    const float* b2 = (const float*)d_in[5];
    const float* W3 = (const float*)d_in[6];
    const float* b3 = (const float*)d_in[7];
    const float* W4 = (const float*)d_in[8];
    const float* b4 = (const float*)d_in[9];

    const int N = in_sizes[0] / 32;
    const int E = in_sizes[1] / 2;
    const int* src = ei;
    const int* dst = ei + E;

    const int NBKT = (N + BKT_NODES - 1) >> BKT_SHIFT;   // 782
    const int SBLK = (E + EPB - 1) / EPB;                // 306
    const int LINB = (N + 511) / 512;                    // 196

    char* ws = (char*)d_ws;
    size_t o = 0;
    auto alloc = [&](size_t bytes) -> char* {
        o = (o + 255) & ~(size_t)255;
        char* r = ws + o;
        o += bytes;
        return r;
    };
    int*      gcnt   = (int*)     alloc(4 * (size_t)NBKT);
    int*      staged = (int*)     alloc(4 * (size_t)NBKT * BCAP);   // 25.6 MB
    ushort_t* zb     = (ushort_t*)alloc(2 * (size_t)N * 16);        // z1 = x@W1
    ushort_t* z2b    = (ushort_t*)alloc(2 * (size_t)N * 16);        // z2 = relu(out1)@W3

    (void)hipMemsetAsync(gcnt, 0, 4 * (size_t)NBKT, stream);

    scatter_lin<<<SBLK + LINB, 512, 0, stream>>>(
        src, dst, gcnt, staged, (const float4*)x, W1, zb, E, SBLK, N, NBKT);

    agg_sort_mlp<true ><<<NBKT, 256, 0, stream>>>(
        zb, staged, gcnt, b1, W2, b2, W3, z2b, N);
    agg_sort_mlp<false><<<NBKT, 256, 0, stream>>>(
        z2b, staged, gcnt, b3, W4, b4, nullptr, (float*)d_out, N);
}

// Round 10
// 180.517 us; speedup vs baseline: 1.0896x; 1.0896x over previous
//
#include <hip/hip_runtime.h>

typedef unsigned short ushort_t;
typedef unsigned int uint_t;

#define BKT_SHIFT 6            // 64 dst-nodes per bucket
#define BKT_NODES 64
#define NBKT_MAX 1600          // >= ceil(100000/64)=1563
#define BCAP 2560              // slots/bucket; mean 1600, sigma~40 -> +24 sigma
#define EPB 8192               // edges per scatter block (512 thr x 16 in regs)
#define HCAP 40                // per-(node, src&1) slot capacity; Poisson(12.5)+7.8sig
#define CAPP 81                // padded per-node slot stride (2*HCAP+1, bank-spread)

__device__ __forceinline__ ushort_t f2bf(float f) {
    unsigned u = __float_as_uint(f);
    unsigned r = (u + 0x7FFFu + ((u >> 16) & 1u)) >> 16;   // RNE
    return (ushort_t)r;
}
__device__ __forceinline__ float bflo(uint_t u) { return __uint_as_float(u << 16); }
__device__ __forceinline__ float bfhi(uint_t u) { return __uint_as_float(u & 0xFFFF0000u); }

// ---- fat kernel: range-claim bucket scatter  ||  z1 = x @ W1 (bf16) ----
// (round-4 scatter verbatim — the 177.4us-validated version; 64-node geom.)
// Scatter blocks: 16 edges/thread in REGISTERS; LDS histogram; ONE global
// atomicAdd per (block,bucket) claims a contiguous range (~306 claims per
// address); place via LDS rank atomics. Per-edge atomics stay in LDS.
// Lin blocks: per-node 32->16 matvec, bf16 out (GIN distributivity:
// (x_i + sum x_j)@W1 = z_i + sum z_j -> aggregate in 16-ch z-space;
// z table = 3.2 MB -> per-XCD-L2-resident, gather order irrelevant).
__global__ __launch_bounds__(512) void scatter_lin(
    const int* __restrict__ src, const int* __restrict__ dst,
    int* __restrict__ gcnt, int* __restrict__ staged,
    const float4* __restrict__ x4, const float* __restrict__ W,
    ushort_t* __restrict__ z, int E, int SBLK, int N, int NBKT)
{
    __shared__ float sW[512];
    __shared__ int lcnt[NBKT_MAX];
    __shared__ int lbase[NBKT_MAX];
    __shared__ int lcur[NBKT_MAX];
    int t = threadIdx.x, blk = blockIdx.x;
    if (blk < SBLK) {
        for (int b = t; b < NBKT; b += 512) { lcnt[b] = 0; lcur[b] = 0; }
        __syncthreads();
        int e0 = blk * EPB;
        int rd[16], rs[16];
        #pragma unroll
        for (int i = 0; i < 16; ++i) {
            int e = e0 + i * 512 + t;
            bool ok = (e < E);
            rd[i] = ok ? dst[e] : -1;
            rs[i] = ok ? src[e] : 0;
            if (ok) atomicAdd(&lcnt[rd[i] >> BKT_SHIFT], 1);
        }
        __syncthreads();
        for (int b = t; b < NBKT; b += 512)
            lbase[b] = atomicAdd(&gcnt[b], lcnt[b]);
        __syncthreads();
        #pragma unroll
        for (int i = 0; i < 16; ++i) {
            if (rd[i] >= 0) {
                int b = rd[i] >> BKT_SHIFT;
                int r = lbase[b] + atomicAdd(&lcur[b], 1);
                if (r < BCAP)   // statistically unreachable overflow guard
                    staged[(size_t)b * BCAP + r] =
                        ((rd[i] & (BKT_NODES - 1)) << 24) | rs[i];
            }
        }
    } else {
        sW[t] = W[t];                      // 32x16 = 512 floats
        __syncthreads();
        int n = (blk - SBLK) * 512 + t;
        if (n >= N) return;
        float a[16];
        #pragma unroll
        for (int c = 0; c < 16; ++c) a[c] = 0.f;
        const float4* xr = x4 + (size_t)n * 8;
        #pragma unroll
        for (int k4 = 0; k4 < 8; ++k4) {
            float4 xv = xr[k4];
            #pragma unroll
            for (int c = 0; c < 16; ++c) {
                a[c] += xv.x * sW[(k4 * 4 + 0) * 16 + c];
                a[c] += xv.y * sW[(k4 * 4 + 1) * 16 + c];
                a[c] += xv.z * sW[(k4 * 4 + 2) * 16 + c];
                a[c] += xv.w * sW[(k4 * 4 + 3) * 16 + c];
            }
        }
        uint_t w[8];
        #pragma unroll
        for (int i2 = 0; i2 < 8; ++i2)
            w[i2] = (uint_t)f2bf(a[2 * i2]) | ((uint_t)f2bf(a[2 * i2 + 1]) << 16);
        uint4* zo = (uint4*)(z + (size_t)n * 16);
        uint4 q0; q0.x = w[0]; q0.y = w[1]; q0.z = w[2]; q0.w = w[3];
        uint4 q1; q1.x = w[4]; q1.y = w[5]; q1.z = w[6]; q1.w = w[7];
        zo[0] = q0;     // cacheable: consumed by agg gathers next
        zo[1] = q1;
    }
}

// ---- Fused single-pass bucket + aggregate + MLP ------------------------
// Round-9 PMC: old sort-based agg = 49us, VALUBusy 12%, HBM 12%, Occ 26%
// -> latency-bound with too few blocks (782=3/CU) and ~20 serial barriers.
// Fix: (a) 64-node buckets -> 1563 blocks ~6/CU, ~38KB LDS -> 4 blk/CU;
// (b) count+scan+place sort (2 global passes + 14-barrier scan) replaced by
// ONE pass direct slotting: per-(node, src&1) fixed-capacity LDS lists
// (stride 81 = bank-spread; capacity 40 = +7.8sigma over Poisson(12.5)).
// Phase 2 = round-4 verified 4-lane/uint2 gather + LDS-staged MLP.
//   CHAIN:  z_next = ReLU(o)@Wc -> bf16 (feeds conv2's aggregation)
//   !CHAIN: o -> fp32 final output

template <bool CHAIN>
__global__ __launch_bounds__(256) void agg_slot_mlp(
    const ushort_t* __restrict__ zin, const int* __restrict__ staged,
    const int* __restrict__ gcnt,
    const float* __restrict__ ba,
    const float* __restrict__ Wb, const float* __restrict__ bb,
    const float* __restrict__ Wc,
    void* __restrict__ outv, int N)
{
    __shared__ float sWb[512];     // 16x32
    __shared__ float sWc[512];     // 32x16 (CHAIN only)
    __shared__ float sba[16], sbb[32];
    __shared__ float sh[BKT_NODES * 17];
    __shared__ float sr[BKT_NODES * 33];
    __shared__ int cnt2[BKT_NODES * 2];
    __shared__ int slots[BKT_NODES * CAPP];   // 20.7 KB

    int t = threadIdx.x;
    sWb[t] = Wb[t];  sWb[t + 256] = Wb[t + 256];
    if (CHAIN) { sWc[t] = Wc[t];  sWc[t + 256] = Wc[t + 256]; }
    if (t < 16) sba[t] = ba[t];
    if (t < 32) sbb[t] = bb[t];
    if (t < BKT_NODES * 2) cnt2[t] = 0;
    __syncthreads();

    int b = blockIdx.x;
    int m = min(gcnt[b], BCAP);
    const int* sp = staged + (size_t)b * BCAP;

    // ONE pass: direct-slot each edge (no count pass, no scan, no re-read)
    for (int i = t; i < m; i += 256) {
        int v = sp[i];
        int dl = ((unsigned)v) >> 24;
        int h = v & 1;                     // src-parity subkey halves contention
        int r = atomicAdd(&cnt2[dl * 2 + h], 1);
        if (r < HCAP)   // statistically unreachable overflow guard
            slots[dl * CAPP + h * HCAP + r] = v & 0xFFFFFF;
    }
    __syncthreads();

    // gather + accumulate (round-4 verified 4-lane/uint2 core, 2 segments)
    int ln = t >> 2;          // node slot 0..63
    int sl = t & 3;           // channels 4*sl .. 4*sl+3
    int n  = (b << BKT_SHIFT) + ln;
    bool act = (n < N);
    const uint2* zp = (const uint2*)zin;   // row = 4 uint2 (16 bf16)

    if (act) {
        uint2 us = zp[(size_t)n * 4 + sl];
        float v0 = bflo(us.x), v1 = bfhi(us.x), v2 = bflo(us.y), v3 = bfhi(us.y);
        #pragma unroll
        for (int h = 0; h < 2; ++h) {
            int kend = min(cnt2[ln * 2 + h], HCAP);
            const int* sl0 = &slots[ln * CAPP + h * HCAP];
            int k = 0;
            for (; k + 8 <= kend; k += 8) {
                int s0 = sl0[k + 0], s1 = sl0[k + 1], s2 = sl0[k + 2], s3 = sl0[k + 3];
                int s4 = sl0[k + 4], s5 = sl0[k + 5], s6 = sl0[k + 6], s7 = sl0[k + 7];
                uint2 u0 = zp[(size_t)s0 * 4 + sl];
                uint2 u1 = zp[(size_t)s1 * 4 + sl];
                uint2 u2 = zp[(size_t)s2 * 4 + sl];
                uint2 u3 = zp[(size_t)s3 * 4 + sl];
                uint2 u4 = zp[(size_t)s4 * 4 + sl];
                uint2 u5 = zp[(size_t)s5 * 4 + sl];
                uint2 u6 = zp[(size_t)s6 * 4 + sl];
                uint2 u7 = zp[(size_t)s7 * 4 + sl];
                v0 += ((bflo(u0.x) + bflo(u1.x)) + (bflo(u2.x) + bflo(u3.x)))
                    + ((bflo(u4.x) + bflo(u5.x)) + (bflo(u6.x) + bflo(u7.x)));
                v1 += ((bfhi(u0.x) + bfhi(u1.x)) + (bfhi(u2.x) + bfhi(u3.x)))
                    + ((bfhi(u4.x) + bfhi(u5.x)) + (bfhi(u6.x) + bfhi(u7.x)));
                v2 += ((bflo(u0.y) + bflo(u1.y)) + (bflo(u2.y) + bflo(u3.y)))
                    + ((bflo(u4.y) + bflo(u5.y)) + (bflo(u6.y) + bflo(u7.y)));
                v3 += ((bfhi(u0.y) + bfhi(u1.y)) + (bfhi(u2.y) + bfhi(u3.y)))
                    + ((bfhi(u4.y) + bfhi(u5.y)) + (bfhi(u6.y) + bfhi(u7.y)));
            }
            for (; k < kend; ++k) {
                uint2 u = zp[(size_t)sl0[k] * 4 + sl];
                v0 += bflo(u.x); v1 += bfhi(u.x); v2 += bflo(u.y); v3 += bfhi(u.y);
            }
        }
        int cb = sl * 4;
        sh[ln * 17 + cb + 0] = fmaxf(v0 + sba[cb + 0], 0.f);
        sh[ln * 17 + cb + 1] = fmaxf(v1 + sba[cb + 1], 0.f);
        sh[ln * 17 + cb + 2] = fmaxf(v2 + sba[cb + 2], 0.f);
        sh[ln * 17 + cb + 3] = fmaxf(v3 + sba[cb + 3], 0.f);
    }
    __syncthreads();

    if (act) {   // out channels 8*sl .. 8*sl+7 of o = h@Wb + bb
        int c0 = sl * 8;
        float o[8];
        #pragma unroll
        for (int j = 0; j < 8; ++j) o[j] = sbb[c0 + j];
        #pragma unroll
        for (int j = 0; j < 16; ++j) {
            float hj = sh[ln * 17 + j];
            #pragma unroll
            for (int cc = 0; cc < 8; ++cc)
                o[cc] += hj * sWb[j * 32 + c0 + cc];
        }
        if (CHAIN) {
            #pragma unroll
            for (int cc = 0; cc < 8; ++cc)
                sr[ln * 33 + c0 + cc] = fmaxf(o[cc], 0.f);
        } else {
            float* op = (float*)outv + (size_t)n * 32 + c0;
            #pragma unroll
            for (int cc = 0; cc < 8; ++cc)
                __builtin_nontemporal_store(o[cc], op + cc);
        }
    }
    if (CHAIN) {
        __syncthreads();
        if (act) {   // z_next channels 4*sl .. 4*sl+3 = ReLU(o) @ Wc
            int c0 = sl * 4;
            float a0 = 0.f, a1 = 0.f, a2 = 0.f, a3 = 0.f;
            #pragma unroll
            for (int j = 0; j < 32; ++j) {
                float rj = sr[ln * 33 + j];
                a0 += rj * sWc[j * 16 + c0 + 0];
                a1 += rj * sWc[j * 16 + c0 + 1];
                a2 += rj * sWc[j * 16 + c0 + 2];
                a3 += rj * sWc[j * 16 + c0 + 3];
            }
            uint_t p0 = (uint_t)f2bf(a0) | ((uint_t)f2bf(a1) << 16);
            uint_t p1 = (uint_t)f2bf(a2) | ((uint_t)f2bf(a3) << 16);
            uint_t* op = (uint_t*)outv + (size_t)n * 8 + sl * 2;
            op[0] = p0;    // cacheable: consumed by next conv's gather
            op[1] = p1;
        }
    }
}

// ---- Launch -------------------------------------------------------------

extern "C" void kernel_launch(void* const* d_in, const int* in_sizes, int n_in,
                              void* d_out, int out_size, void* d_ws, size_t ws_size,
                              hipStream_t stream) {
    const float* x  = (const float*)d_in[0];
    const int*   ei = (const int*)d_in[1];
    const float* W1 = (const float*)d_in[2];
    const float* b1 = (const float*)d_in[3];
    const float* W2 = (const float*)d_in[4];
    const float* b2 = (const float*)d_in[5];
    const float* W3 = (const float*)d_in[6];
    const float* b3 = (const float*)d_in[7];
    const float* W4 = (const float*)d_in[8];
    const float* b4 = (const float*)d_in[9];

    const int N = in_sizes[0] / 32;
    const int E = in_sizes[1] / 2;
    const int* src = ei;
    const int* dst = ei + E;

    const int NBKT = (N + BKT_NODES - 1) >> BKT_SHIFT;   // 1563
    const int SBLK = (E + EPB - 1) / EPB;                // 306
    const int LINB = (N + 511) / 512;                    // 196

    char* ws = (char*)d_ws;
    size_t o = 0;
    auto alloc = [&](size_t bytes) -> char* {
        o = (o + 255) & ~(size_t)255;
        char* r = ws + o;
        o += bytes;
        return r;
    };
    int*      gcnt   = (int*)     alloc(4 * (size_t)NBKT);
    int*      staged = (int*)     alloc(4 * (size_t)NBKT * BCAP);   // 16 MB
    ushort_t* zb     = (ushort_t*)alloc(2 * (size_t)N * 16);        // z1 = x@W1
    ushort_t* z2b    = (ushort_t*)alloc(2 * (size_t)N * 16);        // z2 = relu(out1)@W3

    (void)hipMemsetAsync(gcnt, 0, 4 * (size_t)NBKT, stream);

    scatter_lin<<<SBLK + LINB, 512, 0, stream>>>(
        src, dst, gcnt, staged, (const float4*)x, W1, zb, E, SBLK, N, NBKT);

    agg_slot_mlp<true ><<<NBKT, 256, 0, stream>>>(
        zb, staged, gcnt, b1, W2, b2, W3, z2b, N);
    agg_slot_mlp<false><<<NBKT, 256, 0, stream>>>(
        z2b, staged, gcnt, b3, W4, b4, nullptr, (float*)d_out, N);
}